// Round 1
// baseline (1318.092 us; speedup 1.0000x reference)
//
#include <hip/hip_runtime.h>
#include <hip/hip_bf16.h>

// Problem constants
// x: (64,3,384,384) f32; conv_w: (768,3,16,16) f32; conv_b: (768,) f32; latent: (1,1024,768) f32
// patches: 24x24=576 per image, M = 64*576 = 36864 rows, K = 3*16*16 = 768, D = 768, L = 1024
#define MROWS 36864
#define KDIM  768
#define NPATCH 576
#define NBATCH 64
#define LROWS 1024

typedef __attribute__((ext_vector_type(8))) short short8;
typedef __attribute__((ext_vector_type(4))) float float4v;

__device__ inline short f2bf(float f) {
    unsigned u = __builtin_bit_cast(unsigned, f);
    unsigned r = (u + 0x7FFFu + ((u >> 16) & 1u)) >> 16;
    return (short)r;
}
__device__ inline float bf2f(short s) {
    unsigned u = ((unsigned)(unsigned short)s) << 16;
    return __builtin_bit_cast(float, u);
}

// ---- im2col + cast to bf16: A[row, k], row = b*576 + ph*24 + pw, k = c*256 + i*16 + j
__global__ void im2col_cast(const float* __restrict__ x, short* __restrict__ A, int total) {
    int t = blockIdx.x * blockDim.x + threadIdx.x;
    if (t >= total) return;
    int row = t / KDIM;
    int k = t - row * KDIM;
    int c = k >> 8;
    int rem = k & 255;
    int i = rem >> 4;
    int j = rem & 15;
    int b = row / NPATCH;
    int p = row - b * NPATCH;
    int ph = p / 24;
    int pw = p - ph * 24;
    float v = x[(((size_t)b * 3 + c) * 384 + ph * 16 + i) * 384 + pw * 16 + j];
    A[t] = f2bf(v);
}

__global__ void cast_f32_bf16(const float* __restrict__ src, short* __restrict__ dst, int n) {
    int t = blockIdx.x * blockDim.x + threadIdx.x;
    if (t < n) dst[t] = f2bf(src[t]);
}

// ---- conv GEMM: patch[m, n] = sum_k A[m,k] * Wm[n,k] + bias[n], store bf16
__global__ __launch_bounds__(256) void gemm_conv(const short* __restrict__ A,
                                                 const short* __restrict__ Wm,
                                                 const float* __restrict__ bias,
                                                 short* __restrict__ patch) {
    int blk = blockIdx.x;
    int mb = blk / 12, nb = blk - mb * 12;        // 576 x 12 blocks of 64x64
    int wave = threadIdx.x >> 6, lane = threadIdx.x & 63;
    int quad = lane >> 4, l15 = lane & 15;
    int m_base = mb * 64 + wave * 16;
    int n_base = nb * 64;
    float4v acc[4] = {};
    const short* arow = A + (size_t)(m_base + l15) * KDIM;
    for (int ks = 0; ks < KDIM; ks += 32) {
        short8 a = *(const short8*)(arow + ks + quad * 8);
#pragma unroll
        for (int t = 0; t < 4; t++) {
            short8 b = *(const short8*)(Wm + (size_t)(n_base + t * 16 + l15) * KDIM + ks + quad * 8);
            acc[t] = __builtin_amdgcn_mfma_f32_16x16x32_bf16(a, b, acc[t], 0, 0, 0);
        }
    }
#pragma unroll
    for (int t = 0; t < 4; t++) {
        int n = n_base + t * 16 + l15;
        float bv = bias[n];
#pragma unroll
        for (int r = 0; r < 4; r++) {
            int m = m_base + quad * 4 + r;
            patch[(size_t)m * KDIM + n] = f2bf(acc[t][r] + bv);
        }
    }
}

// ---- row L2-normalize (bf16 in -> bf16 out), one wave per row of 768
__global__ __launch_bounds__(256) void normalize_rows_bf16(const short* __restrict__ src,
                                                           short* __restrict__ dst) {
    int wave = threadIdx.x >> 6, lane = threadIdx.x & 63;
    size_t row = (size_t)blockIdx.x * 4 + wave;
    const short* pr = src + row * KDIM;
    float v[12];
    float ss = 0.f;
#pragma unroll
    for (int i = 0; i < 12; i++) {
        v[i] = bf2f(pr[lane + 64 * i]);
        ss += v[i] * v[i];
    }
#pragma unroll
    for (int off = 32; off; off >>= 1) ss += __shfl_xor(ss, off);
    float norm = sqrtf(ss);
    float scale = 1.0f / fmaxf(norm, 1e-8f);
    short* dr = dst + row * KDIM;
#pragma unroll
    for (int i = 0; i < 12; i++) dr[lane + 64 * i] = f2bf(v[i] * scale);
}

// ---- row L2-normalize (f32 in -> bf16 out) for latent
__global__ __launch_bounds__(256) void normalize_rows_f32(const float* __restrict__ src,
                                                          short* __restrict__ dst) {
    int wave = threadIdx.x >> 6, lane = threadIdx.x & 63;
    size_t row = (size_t)blockIdx.x * 4 + wave;
    const float* pr = src + row * KDIM;
    float v[12];
    float ss = 0.f;
#pragma unroll
    for (int i = 0; i < 12; i++) {
        v[i] = pr[lane + 64 * i];
        ss += v[i] * v[i];
    }
#pragma unroll
    for (int off = 32; off; off >>= 1) ss += __shfl_xor(ss, off);
    float norm = sqrtf(ss);
    float scale = 1.0f / fmaxf(norm, 1e-8f);
    short* dr = dst + row * KDIM;
#pragma unroll
    for (int i = 0; i < 12; i++) dr[lane + 64 * i] = f2bf(v[i] * scale);
}

// ---- SIM GEMM: per batch, sum over off-diag of exp(2 * pn_b . pn_b^T)
__global__ __launch_bounds__(256) void gemm_sim(const short* __restrict__ pn,
                                                float* __restrict__ far_sum) {
    int blk = blockIdx.x;                 // 64 * 81 blocks
    int b = blk / 81;
    int r2 = blk - b * 81;
    int mb = r2 / 9, nb = r2 - mb * 9;    // 9x9 blocks of 64x64 within a 576x576 matrix
    int wave = threadIdx.x >> 6, lane = threadIdx.x & 63;
    int quad = lane >> 4, l15 = lane & 15;
    int m_in_b = mb * 64 + wave * 16;     // row within batch
    int n_in_b = nb * 64;                 // col base within batch
    const short* arow = pn + ((size_t)b * NPATCH + m_in_b + l15) * KDIM;
    const short* qbase = pn + ((size_t)b * NPATCH + n_in_b) * KDIM;
    float4v acc[4] = {};
    for (int ks = 0; ks < KDIM; ks += 32) {
        short8 a = *(const short8*)(arow + ks + quad * 8);
#pragma unroll
        for (int t = 0; t < 4; t++) {
            short8 bq = *(const short8*)(qbase + (size_t)(t * 16 + l15) * KDIM + ks + quad * 8);
            acc[t] = __builtin_amdgcn_mfma_f32_16x16x32_bf16(a, bq, acc[t], 0, 0, 0);
        }
    }
    float s = 0.f;
#pragma unroll
    for (int t = 0; t < 4; t++) {
        int c = n_in_b + t * 16 + l15;
#pragma unroll
        for (int r = 0; r < 4; r++) {
            int rr = m_in_b + quad * 4 + r;
            if (rr != c) s += __expf(2.0f * acc[t][r]);
        }
    }
#pragma unroll
    for (int off = 32; off; off >>= 1) s += __shfl_down(s, off);
    __shared__ float red[4];
    if (lane == 0) red[wave] = s;
    __syncthreads();
    if (threadIdx.x == 0) atomicAdd(&far_sum[b], red[0] + red[1] + red[2] + red[3]);
}

// ---- close GEMM: sum of exp(2 * pn . ln^T) per batch
__global__ __launch_bounds__(256) void gemm_close(const short* __restrict__ pn,
                                                  const short* __restrict__ ln,
                                                  float* __restrict__ close_sum) {
    int blk = blockIdx.x;                 // 576 x 16 blocks of 64x64
    int mb = blk / 16, nb = blk - mb * 16;
    int b = mb / 9;                       // 9 m-blocks (64 rows) per batch (576 rows)
    int wave = threadIdx.x >> 6, lane = threadIdx.x & 63;
    int quad = lane >> 4, l15 = lane & 15;
    int m_base = mb * 64 + wave * 16;
    int n_base = nb * 64;
    const short* arow = pn + (size_t)(m_base + l15) * KDIM;
    float4v acc[4] = {};
    for (int ks = 0; ks < KDIM; ks += 32) {
        short8 a = *(const short8*)(arow + ks + quad * 8);
#pragma unroll
        for (int t = 0; t < 4; t++) {
            short8 bq = *(const short8*)(ln + (size_t)(n_base + t * 16 + l15) * KDIM + ks + quad * 8);
            acc[t] = __builtin_amdgcn_mfma_f32_16x16x32_bf16(a, bq, acc[t], 0, 0, 0);
        }
    }
    float s = 0.f;
#pragma unroll
    for (int t = 0; t < 4; t++) {
#pragma unroll
        for (int r = 0; r < 4; r++) s += __expf(2.0f * acc[t][r]);
    }
#pragma unroll
    for (int off = 32; off; off >>= 1) s += __shfl_down(s, off);
    __shared__ float red[4];
    if (lane == 0) red[wave] = s;
    __syncthreads();
    if (threadIdx.x == 0) atomicAdd(&close_sum[b], red[0] + red[1] + red[2] + red[3]);
}

// ---- final loss: mean over 64 batches of log(far) - log(close)
__global__ void loss_kernel(const float* __restrict__ far_sum,
                            const float* __restrict__ close_sum,
                            float* __restrict__ out) {
    int t = threadIdx.x;  // 64 threads
    float v = logf(far_sum[t]) - logf(close_sum[t]);
#pragma unroll
    for (int off = 32; off; off >>= 1) v += __shfl_xor(v, off);
    if (t == 0) out[0] = v * (1.0f / 64.0f);
}

extern "C" void kernel_launch(void* const* d_in, const int* in_sizes, int n_in,
                              void* d_out, int out_size, void* d_ws, size_t ws_size,
                              hipStream_t stream) {
    const float* x      = (const float*)d_in[0];
    const float* conv_w = (const float*)d_in[1];
    const float* conv_b = (const float*)d_in[2];
    const float* latent = (const float*)d_in[3];
    float* out = (float*)d_out;
    char* ws = (char*)d_ws;

    // workspace layout (bytes)
    // A (im2col bf16):  0            .. 56,623,104   (reused as pn after conv GEMM)
    // Wm (bf16):        56,623,104   .. 57,802,752
    // Lm (bf16):        57,802,752   .. 59,375,616
    // patch (bf16):     59,375,616   .. 115,998,720
    // sums (f32 x128):  115,998,720  .. 115,999,232
    short* A     = (short*)ws;
    short* Wm    = (short*)(ws + 56623104);
    short* Lm    = (short*)(ws + 57802752);
    short* patch = (short*)(ws + 59375616);
    float* sums  = (float*)(ws + 115998720);
    short* pn = A;  // reuse A region once conv GEMM is done
    float* far_sum = sums;
    float* close_sum = sums + 64;

    hipMemsetAsync(sums, 0, 128 * sizeof(float), stream);

    int total_A = MROWS * KDIM;  // 28,311,552
    im2col_cast<<<total_A / 256, 256, 0, stream>>>(x, A, total_A);
    cast_f32_bf16<<<(768 * 768 + 255) / 256, 256, 0, stream>>>(conv_w, Wm, 768 * 768);

    // latent: normalize directly from f32 -> bf16 (1024 rows)
    normalize_rows_f32<<<LROWS / 4, 256, 0, stream>>>(latent, Lm);

    gemm_conv<<<576 * 12, 256, 0, stream>>>(A, Wm, conv_b, patch);

    normalize_rows_bf16<<<MROWS / 4, 256, 0, stream>>>(patch, pn);

    gemm_sim<<<NBATCH * 81, 256, 0, stream>>>(pn, far_sum);
    gemm_close<<<576 * 16, 256, 0, stream>>>(pn, Lm, close_sum);

    loss_kernel<<<1, 64, 0, stream>>>(far_sum, close_sum, out);
}

// Round 2
// 446.874 us; speedup vs baseline: 2.9496x; 2.9496x over previous
//
#include <hip/hip_runtime.h>
#include <hip/hip_bf16.h>

// x: (64,3,384,384) f32; conv_w: (768,3,16,16) f32; conv_b: (768,) f32; latent: (1,1024,768) f32
// patches 24x24=576/img, M=36864, K=768, L=1024. pn padded to 640 rows/batch (5x128 tiles).
#define KDIM   768
#define NPATCH 576
#define NPAD   640
#define NBATCH 64
#define MROWS  36864
#define MPAD   40960
#define LROWS  1024

typedef __attribute__((ext_vector_type(8))) short short8;
typedef __attribute__((ext_vector_type(4))) short short4v;
typedef __attribute__((ext_vector_type(4))) float float4v;

__device__ inline short f2bf(float f) {
    unsigned u = __builtin_bit_cast(unsigned, f);
    unsigned r = (u + 0x7FFFu + ((u >> 16) & 1u)) >> 16;
    return (short)r;
}
__device__ inline float bf2f(short s) {
    unsigned u = ((unsigned)(unsigned short)s) << 16;
    return __builtin_bit_cast(float, u);
}

__device__ __forceinline__ void gload_lds16(const short* g, short* l) {
    __builtin_amdgcn_global_load_lds(
        (const __attribute__((address_space(1))) unsigned int*)g,
        (__attribute__((address_space(3))) unsigned int*)l, 16, 0, 0);
}

// ---------------- im2col + bf16 cast, 16 contiguous floats per thread ----------------
__global__ __launch_bounds__(256) void im2col_cast_v(const float* __restrict__ x,
                                                     short* __restrict__ A) {
    int t = blockIdx.x * 256 + threadIdx.x;        // 36864*48 threads
    int row = t / 48;
    int ci = t - row * 48;                         // c*16 + i
    int c = ci >> 4, i = ci & 15;
    int b = row / NPATCH;
    int p = row - b * NPATCH;
    int ph = p / 24, pw = p - ph * 24;
    const float* src = x + (((size_t)b * 3 + c) * 384 + ph * 16 + i) * 384 + pw * 16;
    float4v f[4];
#pragma unroll
    for (int q = 0; q < 4; q++) f[q] = *(const float4v*)(src + q * 4);
    short o[16];
#pragma unroll
    for (int q = 0; q < 4; q++)
#pragma unroll
        for (int e = 0; e < 4; e++) o[q * 4 + e] = f2bf(f[q][e]);
    short* dst = A + (size_t)row * KDIM + c * 256 + i * 16;
    *(short8*)dst = *(short8*)&o[0];
    *(short8*)(dst + 8) = *(short8*)&o[8];
}

__global__ __launch_bounds__(256) void cast_w(const float* __restrict__ src,
                                              short* __restrict__ dst) {
    int t = blockIdx.x * 256 + threadIdx.x;        // 589824/4 threads
    float4v f = *(const float4v*)(src + (size_t)t * 4);
    short4v o;
#pragma unroll
    for (int e = 0; e < 4; e++) o[e] = f2bf(f[e]);
    *(short4v*)(dst + (size_t)t * 4) = o;
}

// ---------------- zero the 64 pad rows per batch in pn ----------------
__global__ __launch_bounds__(256) void zero_pads(short* __restrict__ pn) {
    int t = blockIdx.x * 256 + threadIdx.x;        // 64*64*96 threads, short8 each
    int b = t / 6144;
    int rem = t - b * 6144;
    int r = rem / 96, s8 = rem - r * 96;
    short8 z = {};
    *(short8*)(pn + ((size_t)(b * NPAD + NPATCH + r)) * KDIM + s8 * 8) = z;
}

// ---------------- latent: L2-normalize f32 -> bf16, one wave per row ----------------
__global__ __launch_bounds__(256) void normalize_latent(const float* __restrict__ src,
                                                        short* __restrict__ dst) {
    int wave = threadIdx.x >> 6, lane = threadIdx.x & 63;
    int row = blockIdx.x * 4 + wave;               // 256 blocks
    const float4v* pr = (const float4v*)(src + (size_t)row * KDIM);
    float4v v[3];
    float ss = 0.f;
#pragma unroll
    for (int c = 0; c < 3; c++) {
        v[c] = pr[lane + 64 * c];
#pragma unroll
        for (int e = 0; e < 4; e++) ss += v[c][e] * v[c][e];
    }
#pragma unroll
    for (int off = 32; off; off >>= 1) ss += __shfl_xor(ss, off);
    float scale = 1.0f / fmaxf(sqrtf(ss), 1e-8f);
    short4v* dr = (short4v*)(dst + (size_t)row * KDIM);
#pragma unroll
    for (int c = 0; c < 3; c++) {
        short4v o;
#pragma unroll
        for (int e = 0; e < 4; e++) o[e] = f2bf(v[c][e] * scale);
        dr[lane + 64 * c] = o;
    }
}

// ---------------- pn: in-place L2-normalize valid rows (bf16), one wave per row ------
__global__ __launch_bounds__(256) void normalize_pn(short* __restrict__ pn) {
    int wave = threadIdx.x >> 6, lane = threadIdx.x & 63;
    int rr = blockIdx.x * 4 + wave;                // 9216 blocks -> 36864 rows
    int b = rr / NPATCH, p = rr - b * NPATCH;
    short* ptr = pn + ((size_t)b * NPAD + p) * KDIM;
    short8 c0 = *(short8*)(ptr + lane * 8);
    short8 c1 = {};
    float ss = 0.f;
#pragma unroll
    for (int e = 0; e < 8; e++) { float f = bf2f(c0[e]); ss += f * f; }
    if (lane < 32) {
        c1 = *(short8*)(ptr + 512 + lane * 8);
#pragma unroll
        for (int e = 0; e < 8; e++) { float f = bf2f(c1[e]); ss += f * f; }
    }
#pragma unroll
    for (int off = 32; off; off >>= 1) ss += __shfl_xor(ss, off);
    float scale = 1.0f / fmaxf(sqrtf(ss), 1e-8f);
    short8 o0, o1;
#pragma unroll
    for (int e = 0; e < 8; e++) o0[e] = f2bf(bf2f(c0[e]) * scale);
    *(short8*)(ptr + lane * 8) = o0;
    if (lane < 32) {
#pragma unroll
        for (int e = 0; e < 8; e++) o1[e] = f2bf(bf2f(c1[e]) * scale);
        *(short8*)(ptr + 512 + lane * 8) = o1;
    }
}

// ---------------- shared 128x128 GEMM mainloop (C = A . B^T, both row-major K) -------
// 256 threads, 4 waves 2x2, each wave 64x64 = 4x4 frags of 16x16x32 bf16 MFMA.
// LDS tiles 128x32 bf16 staged with global_load_lds width 16.
__device__ __forceinline__ void gemm_mainloop(const short* __restrict__ Ab,
                                              const short* __restrict__ Bb,
                                              short* As, short* Bs,
                                              float4v acc[4][4]) {
    int tid = threadIdx.x;
    int wave = tid >> 6, lane = tid & 63;
    int quad = lane >> 4, l15 = lane & 15;
    int wm = wave & 1, wn = wave >> 1;
    int r0 = (wave << 4) + (lane >> 2);            // staging row for j=0
    int seg = lane & 3;
    const short* ga0 = Ab + (size_t)r0 * KDIM + seg * 8;
    const short* ga1 = ga0 + (size_t)64 * KDIM;
    const short* gb0 = Bb + (size_t)r0 * KDIM + seg * 8;
    const short* gb1 = gb0 + (size_t)64 * KDIM;
    short* lA0 = As + (wave * 16) * 32;            // wave-uniform LDS bases
    short* lA1 = As + (wave * 16 + 64) * 32;
    short* lB0 = Bs + (wave * 16) * 32;
    short* lB1 = Bs + (wave * 16 + 64) * 32;
    for (int ks = 0; ks < KDIM; ks += 32) {
        gload_lds16(ga0 + ks, lA0);
        gload_lds16(ga1 + ks, lA1);
        gload_lds16(gb0 + ks, lB0);
        gload_lds16(gb1 + ks, lB1);
        __syncthreads();
        short8 a[4], b[4];
#pragma unroll
        for (int i = 0; i < 4; i++)
            a[i] = *(const short8*)(As + (wm * 64 + i * 16 + l15) * 32 + quad * 8);
#pragma unroll
        for (int j = 0; j < 4; j++)
            b[j] = *(const short8*)(Bs + (wn * 64 + j * 16 + l15) * 32 + quad * 8);
#pragma unroll
        for (int i = 0; i < 4; i++)
#pragma unroll
            for (int j = 0; j < 4; j++)
                acc[i][j] = __builtin_amdgcn_mfma_f32_16x16x32_bf16(a[i], b[j], acc[i][j], 0, 0, 0);
        __syncthreads();
    }
}

__device__ __forceinline__ float block_reduce_sum(float s, float* red) {
#pragma unroll
    for (int off = 32; off; off >>= 1) s += __shfl_down(s, off);
    int wave = threadIdx.x >> 6, lane = threadIdx.x & 63;
    if (lane == 0) red[wave] = s;
    __syncthreads();
    return red[0] + red[1] + red[2] + red[3];
}

// ---------------- conv GEMM: A(36864x768) . Wm^T(768x768) + bias -> pn strided bf16 --
__global__ __launch_bounds__(256) void gemm_conv(const short* __restrict__ A,
                                                 const short* __restrict__ Wm,
                                                 const float* __restrict__ bias,
                                                 short* __restrict__ pn) {
    __shared__ short As[128 * 32], Bs[128 * 32];
    int mb = blockIdx.x / 6, nb = blockIdx.x - (blockIdx.x / 6) * 6;   // 288 x 6
    int wave = threadIdx.x >> 6, lane = threadIdx.x & 63;
    int quad = lane >> 4, l15 = lane & 15;
    int wm = wave & 1, wn = wave >> 1;
    float4v acc[4][4] = {};
    gemm_mainloop(A + (size_t)mb * 128 * KDIM, Wm + (size_t)nb * 128 * KDIM, As, Bs, acc);
#pragma unroll
    for (int j = 0; j < 4; j++) {
        int col = nb * 128 + wn * 64 + j * 16 + l15;
        float bv = bias[col];
#pragma unroll
        for (int i = 0; i < 4; i++) {
#pragma unroll
            for (int r = 0; r < 4; r++) {
                int row = mb * 128 + wm * 64 + i * 16 + quad * 4 + r;
                int b = row / NPATCH, p = row - b * NPATCH;
                pn[((size_t)b * NPAD + p) * KDIM + col] = f2bf(acc[i][j][r] + bv);
            }
        }
    }
}

// ---------------- SIM GEMM: per batch 640x640 (valid 576), sum off-diag exp(2*sim) ---
__global__ __launch_bounds__(256) void gemm_sim(const short* __restrict__ pn,
                                                float* __restrict__ far_sum) {
    __shared__ short As[128 * 32], Bs[128 * 32];
    __shared__ float red[4];
    int blk = blockIdx.x;                           // 64 * 25
    int b = blk / 25;
    int t = blk - b * 25;
    int mt = t / 5, nt = t - mt * 5;
    int wave = threadIdx.x >> 6, lane = threadIdx.x & 63;
    int quad = lane >> 4, l15 = lane & 15;
    int wm = wave & 1, wn = wave >> 1;
    const short* base = pn + (size_t)b * NPAD * KDIM;
    float4v acc[4][4] = {};
    gemm_mainloop(base + (size_t)mt * 128 * KDIM, base + (size_t)nt * 128 * KDIM, As, Bs, acc);
    float s = 0.f;
#pragma unroll
    for (int i = 0; i < 4; i++) {
#pragma unroll
        for (int j = 0; j < 4; j++) {
            int col = nt * 128 + wn * 64 + j * 16 + l15;
#pragma unroll
            for (int r = 0; r < 4; r++) {
                int row = mt * 128 + wm * 64 + i * 16 + quad * 4 + r;
                if (row < NPATCH && col < NPATCH && row != col)
                    s += __expf(2.0f * acc[i][j][r]);
            }
        }
    }
    float tot = block_reduce_sum(s, red);
    if (threadIdx.x == 0) atomicAdd(&far_sum[b], tot);
}

// ---------------- close GEMM: pn(40960x768) . Lm^T(1024x768), sum exp(2*c) per batch -
__global__ __launch_bounds__(256) void gemm_close(const short* __restrict__ pn,
                                                  const short* __restrict__ Lm,
                                                  float* __restrict__ close_sum) {
    __shared__ short As[128 * 32], Bs[128 * 32];
    __shared__ float red[4];
    int mb = blockIdx.x >> 3, nb = blockIdx.x & 7;  // 320 x 8
    int wave = threadIdx.x >> 6, lane = threadIdx.x & 63;
    int quad = lane >> 4, l15 = lane & 15;
    int wm = wave & 1, wn = wave >> 1;
    float4v acc[4][4] = {};
    gemm_mainloop(pn + (size_t)mb * 128 * KDIM, Lm + (size_t)nb * 128 * KDIM, As, Bs, acc);
    int batch = mb / 5;
    int ptile = (mb - batch * 5) * 128;             // row offset within batch
    float s = 0.f;
#pragma unroll
    for (int i = 0; i < 4; i++) {
#pragma unroll
        for (int r = 0; r < 4; r++) {
            int p = ptile + wm * 64 + i * 16 + quad * 4 + r;
            if (p < NPATCH) {
#pragma unroll
                for (int j = 0; j < 4; j++) s += __expf(2.0f * acc[i][j][r]);
            }
        }
    }
    float tot = block_reduce_sum(s, red);
    if (threadIdx.x == 0) atomicAdd(&close_sum[batch], tot);
}

// ---------------- final loss ----------------
__global__ void loss_kernel(const float* __restrict__ far_sum,
                            const float* __restrict__ close_sum,
                            float* __restrict__ out) {
    int t = threadIdx.x;  // 64
    float v = logf(far_sum[t]) - logf(close_sum[t]);
#pragma unroll
    for (int off = 32; off; off >>= 1) v += __shfl_xor(v, off);
    if (t == 0) out[0] = v * (1.0f / 64.0f);
}

extern "C" void kernel_launch(void* const* d_in, const int* in_sizes, int n_in,
                              void* d_out, int out_size, void* d_ws, size_t ws_size,
                              hipStream_t stream) {
    const float* x      = (const float*)d_in[0];
    const float* conv_w = (const float*)d_in[1];
    const float* conv_b = (const float*)d_in[2];
    const float* latent = (const float*)d_in[3];
    float* out = (float*)d_out;
    char* ws = (char*)d_ws;

    // workspace layout (bytes):
    // pn (40960x768 bf16, 640-strided/batch): 0          .. 62,914,560
    // A  (im2col 36864x768 bf16):             62,914,560 .. 119,537,664
    // Wm (768x768 bf16):                      119,537,664.. 120,717,312
    // Lm (1024x768 bf16):                     120,717,312.. 122,290,176
    // sums (128 f32):                         122,290,176.. 122,290,688
    short* pn = (short*)ws;
    short* A  = (short*)(ws + 62914560);
    short* Wm = (short*)(ws + 119537664);
    short* Lm = (short*)(ws + 120717312);
    float* sums = (float*)(ws + 122290176);
    float* far_sum = sums;
    float* close_sum = sums + 64;

    hipMemsetAsync(sums, 0, 128 * sizeof(float), stream);
    zero_pads<<<1536, 256, 0, stream>>>(pn);
    im2col_cast_v<<<36864 * 48 / 256, 256, 0, stream>>>(x, A);
    cast_w<<<589824 / 4 / 256, 256, 0, stream>>>(conv_w, Wm);
    normalize_latent<<<LROWS / 4, 256, 0, stream>>>(latent, Lm);

    gemm_conv<<<288 * 6, 256, 0, stream>>>(A, Wm, conv_b, pn);
    normalize_pn<<<MROWS / 4, 256, 0, stream>>>(pn);

    gemm_sim<<<NBATCH * 25, 256, 0, stream>>>(pn, far_sum);
    gemm_close<<<320 * 8, 256, 0, stream>>>(pn, Lm, close_sum);

    loss_kernel<<<1, 64, 0, stream>>>(far_sum, close_sum, out);
}

// Round 3
// 403.234 us; speedup vs baseline: 3.2688x; 1.1082x over previous
//
#include <hip/hip_runtime.h>
#include <hip/hip_bf16.h>

// x: (64,3,384,384) f32; conv_w: (768,3,16,16) f32; conv_b: (768,) f32; latent: (1,1024,768) f32
// patches 24x24=576/img, M=36864, K=768, L=1024. pn padded to 640 rows/batch (5x128 tiles).
#define KDIM   768
#define NPATCH 576
#define NPAD   640
#define NBATCH 64
#define MROWS  36864
#define LROWS  1024

typedef __attribute__((ext_vector_type(8))) short short8;
typedef __attribute__((ext_vector_type(4))) short short4v;
typedef __attribute__((ext_vector_type(4))) float float4v;

__device__ inline short f2bf(float f) {
    unsigned u = __builtin_bit_cast(unsigned, f);
    unsigned r = (u + 0x7FFFu + ((u >> 16) & 1u)) >> 16;
    return (short)r;
}

__device__ __forceinline__ void gload_lds16(const short* g, short* l) {
    __builtin_amdgcn_global_load_lds(
        (const __attribute__((address_space(1))) unsigned int*)g,
        (__attribute__((address_space(3))) unsigned int*)l, 16, 0, 0);
}

// ---------------- im2col + bf16 cast, 16 contiguous floats per thread ----------------
__global__ __launch_bounds__(256) void im2col_cast_v(const float* __restrict__ x,
                                                     short* __restrict__ A) {
    int t = blockIdx.x * 256 + threadIdx.x;        // 36864*48 threads
    int row = t / 48;
    int ci = t - row * 48;                         // c*16 + i
    int c = ci >> 4, i = ci & 15;
    int b = row / NPATCH;
    int p = row - b * NPATCH;
    int ph = p / 24, pw = p - ph * 24;
    const float* src = x + (((size_t)b * 3 + c) * 384 + ph * 16 + i) * 384 + pw * 16;
    float4v f[4];
#pragma unroll
    for (int q = 0; q < 4; q++) f[q] = *(const float4v*)(src + q * 4);
    short o[16];
#pragma unroll
    for (int q = 0; q < 4; q++)
#pragma unroll
        for (int e = 0; e < 4; e++) o[q * 4 + e] = f2bf(f[q][e]);
    short* dst = A + (size_t)row * KDIM + c * 256 + i * 16;
    *(short8*)dst = *(short8*)&o[0];
    *(short8*)(dst + 8) = *(short8*)&o[8];
}

__global__ __launch_bounds__(256) void cast_w(const float* __restrict__ src,
                                              short* __restrict__ dst) {
    int t = blockIdx.x * 256 + threadIdx.x;        // 589824/4 threads
    float4v f = *(const float4v*)(src + (size_t)t * 4);
    short4v o;
#pragma unroll
    for (int e = 0; e < 4; e++) o[e] = f2bf(f[e]);
    *(short4v*)(dst + (size_t)t * 4) = o;
}

// ---------------- latent: L2-normalize f32 -> bf16, one wave per row ----------------
__global__ __launch_bounds__(256) void normalize_latent(const float* __restrict__ src,
                                                        short* __restrict__ dst) {
    int wave = threadIdx.x >> 6, lane = threadIdx.x & 63;
    int row = blockIdx.x * 4 + wave;               // 256 blocks
    const float4v* pr = (const float4v*)(src + (size_t)row * KDIM);
    float4v v[3];
    float ss = 0.f;
#pragma unroll
    for (int c = 0; c < 3; c++) {
        v[c] = pr[lane + 64 * c];
#pragma unroll
        for (int e = 0; e < 4; e++) ss += v[c][e] * v[c][e];
    }
#pragma unroll
    for (int off = 32; off; off >>= 1) ss += __shfl_xor(ss, off);
    float scale = 1.0f / fmaxf(sqrtf(ss), 1e-8f);
    short4v* dr = (short4v*)(dst + (size_t)row * KDIM);
#pragma unroll
    for (int c = 0; c < 3; c++) {
        short4v o;
#pragma unroll
        for (int e = 0; e < 4; e++) o[e] = f2bf(v[c][e] * scale);
        dr[lane + 64 * c] = o;
    }
}

// ---------------- inverse row norms from summed squares (padded index space) --------
__global__ __launch_bounds__(256) void inv_norm(const float* __restrict__ rssq,
                                                float* __restrict__ rn) {
    int t = blockIdx.x * 256 + threadIdx.x;        // 160 blocks -> 40960
    int p = t % NPAD;
    rn[t] = (p < NPATCH) ? (1.0f / fmaxf(sqrtf(rssq[t]), 1e-8f)) : 0.0f;
}

// ---------------- shared 128x128 GEMM mainloop (C = A . B^T, both row-major K) -------
// 256 threads, 4 waves 2x2, each wave 64x64 = 4x4 frags of 16x16x32 bf16 MFMA.
// LDS tiles 128x32 bf16 staged with global_load_lds width 16; XOR-swizzled 16B segs
// so every 8-lane b128 phase hits all 8 distinct bank groups (conflict-free).
__device__ __forceinline__ void gemm_mainloop(const short* __restrict__ Ab,
                                              const short* __restrict__ Bb,
                                              short* As, short* Bs,
                                              float4v acc[4][4]) {
    int tid = threadIdx.x;
    int wave = tid >> 6, lane = tid & 63;
    int quad = lane >> 4, l15 = lane & 15;
    int wm = wave & 1, wn = wave >> 1;
    int r0 = (wave << 4) + (lane >> 2);            // staging row for chunk 0
    int g = ((lane & 3) - ((lane >> 3) & 3)) & 3;  // swizzled global 16B-seg
    const short* ga0 = Ab + (size_t)r0 * KDIM + g * 8;
    const short* ga1 = ga0 + (size_t)64 * KDIM;
    const short* gb0 = Bb + (size_t)r0 * KDIM + g * 8;
    const short* gb1 = gb0 + (size_t)64 * KDIM;
    short* lA0 = As + (wave * 16) * 32;            // wave-uniform LDS bases
    short* lA1 = As + (wave * 16 + 64) * 32;
    short* lB0 = Bs + (wave * 16) * 32;
    short* lB1 = Bs + (wave * 16 + 64) * 32;
    int sa = ((quad + (l15 >> 1)) & 3) * 8;        // swizzled read seg (shorts)
    for (int ks = 0; ks < KDIM; ks += 32) {
        gload_lds16(ga0 + ks, lA0);
        gload_lds16(ga1 + ks, lA1);
        gload_lds16(gb0 + ks, lB0);
        gload_lds16(gb1 + ks, lB1);
        __syncthreads();
        short8 a[4], b[4];
#pragma unroll
        for (int i = 0; i < 4; i++)
            a[i] = *(const short8*)(As + (wm * 64 + i * 16 + l15) * 32 + sa);
#pragma unroll
        for (int j = 0; j < 4; j++)
            b[j] = *(const short8*)(Bs + (wn * 64 + j * 16 + l15) * 32 + sa);
#pragma unroll
        for (int i = 0; i < 4; i++)
#pragma unroll
            for (int j = 0; j < 4; j++)
                acc[i][j] = __builtin_amdgcn_mfma_f32_16x16x32_bf16(a[i], b[j], acc[i][j], 0, 0, 0);
        __syncthreads();
    }
}

__device__ __forceinline__ float block_reduce_sum(float s, float* red) {
#pragma unroll
    for (int off = 32; off; off >>= 1) s += __shfl_down(s, off);
    int wave = threadIdx.x >> 6, lane = threadIdx.x & 63;
    if (lane == 0) red[wave] = s;
    __syncthreads();
    return red[0] + red[1] + red[2] + red[3];
}

// ---------------- conv GEMM: A . Wm^T + bias -> pn (strided bf16) + row ssq atomics --
__global__ __launch_bounds__(256) void gemm_conv(const short* __restrict__ A,
                                                 const short* __restrict__ Wm,
                                                 const float* __restrict__ bias,
                                                 short* __restrict__ pn,
                                                 float* __restrict__ rssq) {
    __shared__ short As[128 * 32], Bs[128 * 32];
    int xcd = blockIdx.x & 7, q = blockIdx.x >> 3;   // 1728 blocks: 288 mb x 6 nb
    int mb = xcd * 36 + q / 6;                       // contiguous mb strip per XCD
    int nb = q % 6;
    int wave = threadIdx.x >> 6, lane = threadIdx.x & 63;
    int quad = lane >> 4, l15 = lane & 15;
    int wm = wave & 1, wn = wave >> 1;
    float4v acc[4][4] = {};
    gemm_mainloop(A + (size_t)mb * 128 * KDIM, Wm + (size_t)nb * 128 * KDIM, As, Bs, acc);
    float bv[4];
#pragma unroll
    for (int j = 0; j < 4; j++) bv[j] = bias[nb * 128 + wn * 64 + j * 16 + l15];
#pragma unroll
    for (int i = 0; i < 4; i++) {
#pragma unroll
        for (int r = 0; r < 4; r++) {
            int row = mb * 128 + wm * 64 + i * 16 + quad * 4 + r;
            int b = row / NPATCH;
            int prow = row + b * 64;               // padded row index
            float ssq = 0.f;
#pragma unroll
            for (int j = 0; j < 4; j++) {
                int col = nb * 128 + wn * 64 + j * 16 + l15;
                float v = acc[i][j][r] + bv[j];
                ssq += v * v;
                pn[(size_t)prow * KDIM + col] = f2bf(v);
            }
#pragma unroll
            for (int off = 1; off < 16; off <<= 1) ssq += __shfl_xor(ssq, off);
            if (l15 == 0) atomicAdd(&rssq[prow], ssq);
        }
    }
}

// ---------------- SIM GEMM: per batch 640x640 (valid 576), sum off-diag exp(2*cos) --
__global__ __launch_bounds__(256) void gemm_sim(const short* __restrict__ pn,
                                                const float* __restrict__ rn,
                                                float* __restrict__ far_sum) {
    __shared__ short As[128 * 32], Bs[128 * 32];
    __shared__ float red[4];
    int xcd = blockIdx.x & 7, q = blockIdx.x >> 3;   // 1600 blocks: 64 batches x 25
    int b = xcd * 8 + q / 25;                        // 8 batches per XCD
    int t = q % 25;
    int mt = t / 5, nt = t - mt * 5;
    int wave = threadIdx.x >> 6, lane = threadIdx.x & 63;
    int quad = lane >> 4, l15 = lane & 15;
    int wm = wave & 1, wn = wave >> 1;
    const short* base = pn + (size_t)b * NPAD * KDIM;
    float4v acc[4][4] = {};
    gemm_mainloop(base + (size_t)mt * 128 * KDIM, base + (size_t)nt * 128 * KDIM, As, Bs, acc);
    const float* rnb = rn + b * NPAD;
    float rcol[4];
#pragma unroll
    for (int j = 0; j < 4; j++) rcol[j] = rnb[nt * 128 + wn * 64 + j * 16 + l15];
    float s = 0.f;
#pragma unroll
    for (int i = 0; i < 4; i++) {
#pragma unroll
        for (int r = 0; r < 4; r++) {
            int row = mt * 128 + wm * 64 + i * 16 + quad * 4 + r;
            if (row < NPATCH) {
                float rrow = rnb[row];
#pragma unroll
                for (int j = 0; j < 4; j++) {
                    int col = nt * 128 + wn * 64 + j * 16 + l15;
                    if (col < NPATCH && row != col)
                        s += __expf(2.0f * acc[i][j][r] * rrow * rcol[j]);
                }
            }
        }
    }
    float tot = block_reduce_sum(s, red);
    if (threadIdx.x == 0) atomicAdd(&far_sum[b], tot);
}

// ---------------- close GEMM: pn . Lm^T, sum exp(2*cos) per batch --------------------
__global__ __launch_bounds__(256) void gemm_close(const short* __restrict__ pn,
                                                  const short* __restrict__ Lm,
                                                  const float* __restrict__ rn,
                                                  float* __restrict__ close_sum) {
    __shared__ short As[128 * 32], Bs[128 * 32];
    __shared__ float red[4];
    int xcd = blockIdx.x & 7, q = blockIdx.x >> 3;   // 2560 blocks: 320 mb x 8 nb
    int mb = xcd * 40 + (q >> 3);                    // contiguous mb strip per XCD
    int nb = q & 7;
    int wave = threadIdx.x >> 6, lane = threadIdx.x & 63;
    int quad = lane >> 4, l15 = lane & 15;
    int wm = wave & 1, wn = wave >> 1;
    float4v acc[4][4] = {};
    gemm_mainloop(pn + (size_t)mb * 128 * KDIM, Lm + (size_t)nb * 128 * KDIM, As, Bs, acc);
    int batch = mb / 5;
    int ptile = (mb - batch * 5) * 128;              // row offset within batch
    float s = 0.f;
#pragma unroll
    for (int i = 0; i < 4; i++) {
#pragma unroll
        for (int r = 0; r < 4; r++) {
            int p = ptile + wm * 64 + i * 16 + quad * 4 + r;
            if (p < NPATCH) {
                float rrow = rn[batch * NPAD + p];
#pragma unroll
                for (int j = 0; j < 4; j++) s += __expf(2.0f * acc[i][j][r] * rrow);
            }
        }
    }
    float tot = block_reduce_sum(s, red);
    if (threadIdx.x == 0) atomicAdd(&close_sum[batch], tot);
}

// ---------------- final loss ----------------
__global__ void loss_kernel(const float* __restrict__ far_sum,
                            const float* __restrict__ close_sum,
                            float* __restrict__ out) {
    int t = threadIdx.x;  // 64
    float v = logf(far_sum[t]) - logf(close_sum[t]);
#pragma unroll
    for (int off = 32; off; off >>= 1) v += __shfl_xor(v, off);
    if (t == 0) out[0] = v * (1.0f / 64.0f);
}

extern "C" void kernel_launch(void* const* d_in, const int* in_sizes, int n_in,
                              void* d_out, int out_size, void* d_ws, size_t ws_size,
                              hipStream_t stream) {
    const float* x      = (const float*)d_in[0];
    const float* conv_w = (const float*)d_in[1];
    const float* conv_b = (const float*)d_in[2];
    const float* latent = (const float*)d_in[3];
    float* out = (float*)d_out;
    char* ws = (char*)d_ws;

    // workspace layout (bytes):
    // pn (40960x768 bf16, 640 rows/batch):    0          .. 62,914,560
    // A  (im2col 36864x768 bf16):             62,914,560 .. 119,537,664
    //   rn (40960 f32) overlays A (A dead after gemm_conv; rn written after)
    // Wm (768x768 bf16):                      119,537,664.. 120,717,312
    // Lm (1024x768 bf16):                     120,717,312.. 122,290,176
    // rssq (40960 f32) + sums (128 f32):      122,290,176.. 122,454,528
    short* pn = (short*)ws;
    short* A  = (short*)(ws + 62914560);
    short* Wm = (short*)(ws + 119537664);
    short* Lm = (short*)(ws + 120717312);
    float* rssq = (float*)(ws + 122290176);
    float* sums = (float*)(ws + 122454016);
    float* rn   = (float*)(ws + 62914560);   // overlays A
    float* far_sum = sums;
    float* close_sum = sums + 64;

    hipMemsetAsync(rssq, 0, (40960 + 128) * sizeof(float), stream);  // rssq + sums
    im2col_cast_v<<<36864 * 48 / 256, 256, 0, stream>>>(x, A);
    cast_w<<<589824 / 4 / 256, 256, 0, stream>>>(conv_w, Wm);
    normalize_latent<<<LROWS / 4, 256, 0, stream>>>(latent, Lm);

    gemm_conv<<<288 * 6, 256, 0, stream>>>(A, Wm, conv_b, pn, rssq);
    inv_norm<<<160, 256, 0, stream>>>(rssq, rn);

    gemm_sim<<<NBATCH * 25, 256, 0, stream>>>(pn, rn, far_sum);
    gemm_close<<<320 * 8, 256, 0, stream>>>(pn, Lm, rn, close_sum);

    loss_kernel<<<1, 64, 0, stream>>>(far_sum, close_sum, out);
}

// Round 4
// 369.890 us; speedup vs baseline: 3.5635x; 1.0901x over previous
//
#include <hip/hip_runtime.h>
#include <hip/hip_bf16.h>
#include <hip/hip_fp8.h>

// x: (64,3,384,384) f32; conv_w: (768,3,16,16) f32; conv_b: (768,) f32; latent: (1,1024,768) f32
// patches 24x24=576/img, M=36864, K=768, L=1024. pn padded to 640 rows/batch (5x128 tiles).
// All GEMMs in OCP fp8 e4m3 via MX-scaled MFMA 16x16x128 (K-tile 128, 6 iters).
// Scale encoding (e8m0): 127 -> 2^0, 123 -> 2^-4, 122 -> 2^-5.
#define KDIM   768
#define NPATCH 576
#define NPAD   640
#define NBATCH 64
#define MROWS  36864
#define LROWS  1024

typedef __attribute__((ext_vector_type(8))) int int8v;
typedef __attribute__((ext_vector_type(4))) int int4v;
typedef __attribute__((ext_vector_type(4))) float float4v;
typedef unsigned char u8;

__device__ inline u8 f2fp8(float f) { __hip_fp8_e4m3 t(f); return (u8)t.__x; }

__device__ __forceinline__ void gload_lds16(const u8* g, u8* l) {
    __builtin_amdgcn_global_load_lds(
        (const __attribute__((address_space(1))) unsigned int*)g,
        (__attribute__((address_space(3))) unsigned int*)l, 16, 0, 0);
}

// ---------------- im2col + fp8 cast (scale 1), 16 contiguous floats per thread ------
__global__ __launch_bounds__(256) void im2col_cast_v(const float* __restrict__ x,
                                                     u8* __restrict__ A) {
    int t = blockIdx.x * 256 + threadIdx.x;        // 36864*48 threads
    int row = t / 48;
    int ci = t - row * 48;                         // c*16 + i
    int c = ci >> 4, i = ci & 15;
    int b = row / NPATCH;
    int p = row - b * NPATCH;
    int ph = p / 24, pw = p - ph * 24;
    const float* src = x + (((size_t)b * 3 + c) * 384 + ph * 16 + i) * 384 + pw * 16;
    float4v f[4];
#pragma unroll
    for (int q = 0; q < 4; q++) f[q] = *(const float4v*)(src + q * 4);
    unsigned int o[4];
#pragma unroll
    for (int q = 0; q < 4; q++) {
        o[q] = 0;
#pragma unroll
        for (int e = 0; e < 4; e++) o[q] |= ((unsigned int)f2fp8(f[q][e])) << (8 * e);
    }
    *(int4v*)(A + (size_t)row * KDIM + c * 256 + i * 16) = *(int4v*)o;
}

// ---------------- conv_w -> fp8(w*32), used with B-scale 2^-5 ------------------------
__global__ __launch_bounds__(256) void cast_w(const float* __restrict__ src,
                                              u8* __restrict__ dst) {
    int t = blockIdx.x * 256 + threadIdx.x;        // 36864 threads, 16 elems each
    const float* s = src + (size_t)t * 16;
    unsigned int o[4];
#pragma unroll
    for (int q = 0; q < 4; q++) {
        float4v f = *(const float4v*)(s + q * 4);
        o[q] = 0;
#pragma unroll
        for (int e = 0; e < 4; e++) o[q] |= ((unsigned int)f2fp8(f[e] * 32.0f)) << (8 * e);
    }
    *(int4v*)(dst + (size_t)t * 16) = *(int4v*)o;
}

// ---------------- latent: L2-normalize f32 -> fp8(ln*16), one wave per row -----------
__global__ __launch_bounds__(256) void normalize_latent(const float* __restrict__ src,
                                                        u8* __restrict__ dst) {
    int wave = threadIdx.x >> 6, lane = threadIdx.x & 63;
    int row = blockIdx.x * 4 + wave;               // 256 blocks
    const float4v* pr = (const float4v*)(src + (size_t)row * KDIM);
    float4v v[3];
    float ss = 0.f;
#pragma unroll
    for (int c = 0; c < 3; c++) {
        v[c] = pr[lane + 64 * c];
#pragma unroll
        for (int e = 0; e < 4; e++) ss += v[c][e] * v[c][e];
    }
#pragma unroll
    for (int off = 32; off; off >>= 1) ss += __shfl_xor(ss, off);
    float scale = 16.0f / fmaxf(sqrtf(ss), 1e-8f);
#pragma unroll
    for (int c = 0; c < 3; c++) {
        unsigned int o = 0;
#pragma unroll
        for (int e = 0; e < 4; e++) o |= ((unsigned int)f2fp8(v[c][e] * scale)) << (8 * e);
        *(unsigned int*)(dst + (size_t)row * KDIM + c * 256 + lane * 4) = o;
    }
}

// ---------------- inverse row norms from summed squares (padded index space) --------
__global__ __launch_bounds__(256) void inv_norm(const float* __restrict__ rssq,
                                                float* __restrict__ rn) {
    int t = blockIdx.x * 256 + threadIdx.x;        // 160 blocks -> 40960
    int p = t % NPAD;
    rn[t] = (p < NPATCH) ? (1.0f / fmaxf(sqrtf(rssq[t]), 1e-8f)) : 0.0f;
}

// ---------------- fp8 MX GEMM mainloop (C = A . B^T, both row-major K, fp8) ----------
// 256 threads, 4 waves 2x2, each wave 64x64 = 4x4 frags of 16x16x128 scaled MFMA.
// LDS tiles 128x128 fp8 (16 KB each) staged with global_load_lds width 16.
// 32B-granule XOR swizzle by (row&3) -> all b128 phases 2-way max (free).
__device__ __forceinline__ void gemm_mainloop_fp8(const u8* __restrict__ Ab,
                                                  const u8* __restrict__ Bb,
                                                  u8* As, u8* Bs,
                                                  float4v acc[4][4], int sA, int sB) {
    int tid = threadIdx.x;
    int wave = tid >> 6, lane = tid & 63;
    int quad = lane >> 4, l15 = lane & 15;
    int wm = wave & 1, wn = wave >> 1;
    int lrow = lane >> 3, ls = lane & 7;           // staging: 8 lanes x 16B per row
    int gs = ((((ls >> 1) - lrow) & 3) << 1) | (ls & 1);   // swizzled global 16B seg
    const u8* ga = Ab + (size_t)(wave * 32 + lrow) * KDIM + gs * 16;
    const u8* gb = Bb + (size_t)(wave * 32 + lrow) * KDIM + gs * 16;
    u8* lA = As + (wave * 32) * 128;               // wave-uniform LDS bases
    u8* lB = Bs + (wave * 32) * 128;
    int lg = (quad + (l15 & 3)) & 3;               // swizzled LDS granule for reads
    for (int ks = 0; ks < KDIM; ks += 128) {
#pragma unroll
        for (int i = 0; i < 4; i++) {
            gload_lds16(ga + (size_t)(i * 8) * KDIM + ks, lA + i * 8 * 128);
            gload_lds16(gb + (size_t)(i * 8) * KDIM + ks, lB + i * 8 * 128);
        }
        __syncthreads();
        int8v a[4], b[4];
#pragma unroll
        for (int i = 0; i < 4; i++)
            a[i] = *(const int8v*)(As + (wm * 64 + i * 16 + l15) * 128 + lg * 32);
#pragma unroll
        for (int j = 0; j < 4; j++)
            b[j] = *(const int8v*)(Bs + (wn * 64 + j * 16 + l15) * 128 + lg * 32);
#pragma unroll
        for (int i = 0; i < 4; i++)
#pragma unroll
            for (int j = 0; j < 4; j++)
                acc[i][j] = __builtin_amdgcn_mfma_scale_f32_16x16x128_f8f6f4(
                    a[i], b[j], acc[i][j], 0, 0, 0, sA, 0, sB);
        __syncthreads();
    }
}

__device__ __forceinline__ float block_reduce_sum(float s, float* red) {
#pragma unroll
    for (int off = 32; off; off >>= 1) s += __shfl_down(s, off);
    int wave = threadIdx.x >> 6, lane = threadIdx.x & 63;
    if (lane == 0) red[wave] = s;
    __syncthreads();
    return red[0] + red[1] + red[2] + red[3];
}

// ---------------- conv GEMM: A(x,s=1) . Wm^T(w*32,s=2^-5) + bias -> pn fp8(v*16) -----
__global__ __launch_bounds__(256) void gemm_conv(const u8* __restrict__ A,
                                                 const u8* __restrict__ Wm,
                                                 const float* __restrict__ bias,
                                                 u8* __restrict__ pn,
                                                 float* __restrict__ rssq) {
    __shared__ u8 As[128 * 128], Bs[128 * 128];
    int xcd = blockIdx.x & 7, q = blockIdx.x >> 3;   // 1728 blocks: 288 mb x 6 nb
    int mb = xcd * 36 + q / 6;                       // contiguous mb strip per XCD
    int nb = q % 6;
    int wave = threadIdx.x >> 6, lane = threadIdx.x & 63;
    int quad = lane >> 4, l15 = lane & 15;
    int wm = wave & 1, wn = wave >> 1;
    float4v acc[4][4] = {};
    gemm_mainloop_fp8(A + (size_t)mb * 128 * KDIM, Wm + (size_t)nb * 128 * KDIM,
                      As, Bs, acc, 0x7F7F7F7F, 0x7A7A7A7A);
    float bv[4];
#pragma unroll
    for (int j = 0; j < 4; j++) bv[j] = bias[nb * 128 + wn * 64 + j * 16 + l15];
#pragma unroll
    for (int i = 0; i < 4; i++) {
#pragma unroll
        for (int r = 0; r < 4; r++) {
            int row = mb * 128 + wm * 64 + i * 16 + quad * 4 + r;
            int b = row / NPATCH;
            int prow = row + b * 64;               // padded row index
            float ssq = 0.f;
#pragma unroll
            for (int j = 0; j < 4; j++) {
                int col = nb * 128 + wn * 64 + j * 16 + l15;
                float v = acc[i][j][r] + bv[j];
                ssq += v * v;
                pn[(size_t)prow * KDIM + col] = f2fp8(v * 16.0f);
            }
#pragma unroll
            for (int off = 1; off < 16; off <<= 1) ssq += __shfl_xor(ssq, off);
            if (l15 == 0) atomicAdd(&rssq[prow], ssq);
        }
    }
}

// ---------------- SIM GEMM: per batch 640x640 (valid 576), sum off-diag exp(2*cos) --
__global__ __launch_bounds__(256) void gemm_sim(const u8* __restrict__ pn,
                                                const float* __restrict__ rn,
                                                float* __restrict__ far_sum) {
    __shared__ u8 As[128 * 128], Bs[128 * 128];
    __shared__ float red[4];
    int xcd = blockIdx.x & 7, q = blockIdx.x >> 3;   // 1600 blocks: 64 batches x 25
    int b = xcd * 8 + q / 25;                        // 8 batches per XCD
    int t = q % 25;
    int mt = t / 5, nt = t - mt * 5;
    int wave = threadIdx.x >> 6, lane = threadIdx.x & 63;
    int quad = lane >> 4, l15 = lane & 15;
    int wm = wave & 1, wn = wave >> 1;
    const u8* base = pn + (size_t)b * NPAD * KDIM;
    float4v acc[4][4] = {};
    gemm_mainloop_fp8(base + (size_t)mt * 128 * KDIM, base + (size_t)nt * 128 * KDIM,
                      As, Bs, acc, 0x7B7B7B7B, 0x7B7B7B7B);
    const float* rnb = rn + b * NPAD;
    float rcol[4];
#pragma unroll
    for (int j = 0; j < 4; j++) rcol[j] = rnb[nt * 128 + wn * 64 + j * 16 + l15];
    float s = 0.f;
#pragma unroll
    for (int i = 0; i < 4; i++) {
#pragma unroll
        for (int r = 0; r < 4; r++) {
            int row = mt * 128 + wm * 64 + i * 16 + quad * 4 + r;
            if (row < NPATCH) {
                float rrow = rnb[row];
#pragma unroll
                for (int j = 0; j < 4; j++) {
                    int col = nt * 128 + wn * 64 + j * 16 + l15;
                    if (col < NPATCH && row != col)
                        s += __expf(2.0f * acc[i][j][r] * rrow * rcol[j]);
                }
            }
        }
    }
    float tot = block_reduce_sum(s, red);
    if (threadIdx.x == 0) atomicAdd(&far_sum[b], tot);
}

// ---------------- close GEMM: pn . Lm^T (both *16, scales 2^-4), per-batch sums ------
__global__ __launch_bounds__(256) void gemm_close(const u8* __restrict__ pn,
                                                  const u8* __restrict__ Lm,
                                                  const float* __restrict__ rn,
                                                  float* __restrict__ close_sum) {
    __shared__ u8 As[128 * 128], Bs[128 * 128];
    __shared__ float red[4];
    int xcd = blockIdx.x & 7, q = blockIdx.x >> 3;   // 2560 blocks: 320 mb x 8 nb
    int mb = xcd * 40 + (q >> 3);                    // contiguous mb strip per XCD
    int nb = q & 7;
    int wave = threadIdx.x >> 6, lane = threadIdx.x & 63;
    int quad = lane >> 4, l15 = lane & 15;
    int wm = wave & 1, wn = wave >> 1;
    float4v acc[4][4] = {};
    gemm_mainloop_fp8(pn + (size_t)mb * 128 * KDIM, Lm + (size_t)nb * 128 * KDIM,
                      As, Bs, acc, 0x7B7B7B7B, 0x7B7B7B7B);
    int batch = mb / 5;
    int ptile = (mb - batch * 5) * 128;              // row offset within batch
    float s = 0.f;
#pragma unroll
    for (int i = 0; i < 4; i++) {
#pragma unroll
        for (int r = 0; r < 4; r++) {
            int p = ptile + wm * 64 + i * 16 + quad * 4 + r;
            if (p < NPATCH) {
                float rrow = rn[batch * NPAD + p];
#pragma unroll
                for (int j = 0; j < 4; j++) s += __expf(2.0f * acc[i][j][r] * rrow);
            }
        }
    }
    float tot = block_reduce_sum(s, red);
    if (threadIdx.x == 0) atomicAdd(&close_sum[batch], tot);
}

// ---------------- final loss ----------------
__global__ void loss_kernel(const float* __restrict__ far_sum,
                            const float* __restrict__ close_sum,
                            float* __restrict__ out) {
    int t = threadIdx.x;  // 64
    float v = logf(far_sum[t]) - logf(close_sum[t]);
#pragma unroll
    for (int off = 32; off; off >>= 1) v += __shfl_xor(v, off);
    if (t == 0) out[0] = v * (1.0f / 64.0f);
}

extern "C" void kernel_launch(void* const* d_in, const int* in_sizes, int n_in,
                              void* d_out, int out_size, void* d_ws, size_t ws_size,
                              hipStream_t stream) {
    const float* x      = (const float*)d_in[0];
    const float* conv_w = (const float*)d_in[1];
    const float* conv_b = (const float*)d_in[2];
    const float* latent = (const float*)d_in[3];
    float* out = (float*)d_out;
    char* ws = (char*)d_ws;

    // workspace layout (bytes):
    // pn (40960x768 fp8, 640 rows/batch):  0          .. 31,457,280
    // A  (im2col 36864x768 fp8):           31,457,280 .. 59,768,832
    //   rn (40960 f32) overlays A (A dead after gemm_conv; rn written after)
    // Wm (768x768 fp8, *32):               59,768,832 .. 60,358,656
    // Lm (1024x768 fp8, *16):              60,358,656 .. 61,145,088
    // rssq (40960 f32) + sums (128 f32):   61,145,088 .. 61,309,440
    u8* pn = (u8*)ws;
    u8* A  = (u8*)(ws + 31457280);
    u8* Wm = (u8*)(ws + 59768832);
    u8* Lm = (u8*)(ws + 60358656);
    float* rssq = (float*)(ws + 61145088);
    float* sums = (float*)(ws + 61308928);
    float* rn   = (float*)(ws + 31457280);   // overlays A
    float* far_sum = sums;
    float* close_sum = sums + 64;

    hipMemsetAsync(rssq, 0, (40960 + 128) * sizeof(float), stream);  // rssq + sums
    im2col_cast_v<<<36864 * 48 / 256, 256, 0, stream>>>(x, A);
    cast_w<<<144, 256, 0, stream>>>(conv_w, Wm);
    normalize_latent<<<LROWS / 4, 256, 0, stream>>>(latent, Lm);

    gemm_conv<<<288 * 6, 256, 0, stream>>>(A, Wm, conv_b, pn, rssq);
    inv_norm<<<160, 256, 0, stream>>>(rssq, rn);

    gemm_sim<<<NBATCH * 25, 256, 0, stream>>>(pn, rn, far_sum);
    gemm_close<<<320 * 8, 256, 0, stream>>>(pn, Lm, rn, close_sum);

    loss_kernel<<<1, 64, 0, stream>>>(far_sum, close_sum, out);
}